// Round 9
// baseline (118.996 us; speedup 1.0000x reference)
//
#include <hip/hip_runtime.h>

#define H 12
#define DM 768
#define HD 64
#define SEQ 2048
#define BATCH 2
#define MROWS (BATCH*SEQ)   // 4096

typedef __attribute__((ext_vector_type(8))) short short8;   // 8 bf16 (4 VGPRs)
typedef __attribute__((ext_vector_type(4))) float f32x4;
using u16 = unsigned short;
using u32 = unsigned int;

__device__ __forceinline__ float bf2f(u16 u) { return __uint_as_float(((u32)u) << 16); }
__device__ __forceinline__ u16 f2bf(float x) {
  u32 u = __float_as_uint(x);
  return (u16)((u + 0x7fffu + ((u >> 16) & 1u)) >> 16);   // RNE
}
// packed f32x2 -> bf16x2 (RNE), single instruction (T12 recipe: no builtin on gfx950)
__device__ __forceinline__ u32 cvt_pk_bf16(float lo, float hi) {
  u32 r;
  asm("v_cvt_pk_bf16_f32 %0, %1, %2" : "=v"(r) : "v"(lo), "v"(hi));
  return r;
}
// async global->LDS, 16B per lane; LDS dest = wave-uniform base + lane*16 (m97/m104)
__device__ __forceinline__ void gl2lds16(const u16* __restrict__ g, u16* l) {
  __builtin_amdgcn_global_load_lds(
      (const __attribute__((address_space(1))) unsigned int*)g,
      (__attribute__((address_space(3))) unsigned int*)l,
      16, 0, 0);
}

#define C_SM 0.18033688011112042f   // (1/sqrt(64)) * log2(e), folded into K

// ------------- weight transpose + f32->bf16: dst[e*768+d] = bf16(src[d*768+e]) -------------
__global__ __launch_bounds__(256) void transpose_w4(const float* __restrict__ w0, const float* __restrict__ w1,
                                                    const float* __restrict__ w2, const float* __restrict__ w3,
                                                    u16* __restrict__ dst0)
{
  __shared__ u16 Ts[64][72];                 // +8 pad, rows 144 B (16B-aligned)
  const float* src = blockIdx.z == 0 ? w0 : blockIdx.z == 1 ? w1 : blockIdx.z == 2 ? w2 : w3;
  u16* dst = dst0 + (size_t)blockIdx.z * DM * DM;
  const int t = threadIdx.x;
  const int r0 = blockIdx.y * 64, c0 = blockIdx.x * 64;
  const int row = t >> 2, cq = (t & 3) * 16;
  const float* sp = src + (size_t)(r0 + row) * DM + c0 + cq;
  #pragma unroll
  for (int g = 0; g < 4; ++g) {
    float4 a = *reinterpret_cast<const float4*>(sp + g * 4);
    Ts[row][cq + g * 4 + 0] = f2bf(a.x);
    Ts[row][cq + g * 4 + 1] = f2bf(a.y);
    Ts[row][cq + g * 4 + 2] = f2bf(a.z);
    Ts[row][cq + g * 4 + 3] = f2bf(a.w);
  }
  __syncthreads();
  union { uint4 v[2]; u16 e[16]; } pk;
  #pragma unroll
  for (int j = 0; j < 16; ++j) pk.e[j] = Ts[cq + j][row];
  uint4* dp = reinterpret_cast<uint4*>(dst + (size_t)(c0 + row) * DM + r0 + cq);
  dp[0] = pk.v[0];
  dp[1] = pk.v[1];
}

// ---------------- GEMM: C[m][n] = (A[m][:] . Bt[n][:] + bias[n]) * outScale ----------------
// BM x 128 tile, BK=64, 4 waves, wave-tile (BM/2) x 64. Inline staging,
// XOR swizzle byte ^= (row&7)<<4 on write and read (T2, G4). Small BM for occupancy.
template<int BM, bool AF32>
__device__ __forceinline__ void gemm_core(const void* __restrict__ Av, const u16* __restrict__ Bt,
                                          const float* __restrict__ bias, void* __restrict__ dstv,
                                          int mode, int bx, int by, float outScale)
{
  constexpr int AFR = BM / 32;        // A-frags per wave (M dir)
  constexpr int ACH = BM / 32;        // A staging chunks
  __shared__ u16 As[BM * 64];
  __shared__ u16 Bs[128 * 64];
  const int t = threadIdx.x;
  const int lane = t & 63, w = t >> 6;
  const int l15 = lane & 15, l4 = lane >> 4;
  const int m0 = by * BM, n0 = bx * 128;
  const int wr = (w >> 1) * (BM / 2), wc = (w & 1) * 64;

  f32x4 acc[AFR][4] = {};

  for (int kt = 0; kt < DM / 64; ++kt) {
    const int k0 = kt * 64;
    #pragma unroll
    for (int c = 0; c < ACH; ++c) {           // A tile: BM x 64
      const int id = c * 256 + t;
      const int row = id >> 3, xc = id & 7;
      const int db = row * 128 + ((xc * 16) ^ ((row & 7) << 4));
      if (AF32) {
        const float* Af = reinterpret_cast<const float*>(Av) + (size_t)(m0 + row) * DM + k0 + xc * 8;
        float4 a0 = *reinterpret_cast<const float4*>(Af);
        float4 a1 = *reinterpret_cast<const float4*>(Af + 4);
        uint4 v;
        v.x = cvt_pk_bf16(a0.x, a0.y);
        v.y = cvt_pk_bf16(a0.z, a0.w);
        v.z = cvt_pk_bf16(a1.x, a1.y);
        v.w = cvt_pk_bf16(a1.z, a1.w);
        *reinterpret_cast<uint4*>(reinterpret_cast<char*>(As) + db) = v;
      } else {
        uint4 va = *reinterpret_cast<const uint4*>(reinterpret_cast<const u16*>(Av) +
                   (size_t)(m0 + row) * DM + k0 + xc * 8);
        *reinterpret_cast<uint4*>(reinterpret_cast<char*>(As) + db) = va;
      }
    }
    #pragma unroll
    for (int c = 0; c < 4; ++c) {             // B tile: 128 x 64
      const int id = c * 256 + t;
      const int row = id >> 3, xc = id & 7;
      const int db = row * 128 + ((xc * 16) ^ ((row & 7) << 4));
      uint4 vb = *reinterpret_cast<const uint4*>(Bt + (size_t)(n0 + row) * DM + k0 + xc * 8);
      *reinterpret_cast<uint4*>(reinterpret_cast<char*>(Bs) + db) = vb;
    }
    __syncthreads();
    #pragma unroll
    for (int ks = 0; ks < 2; ++ks) {
      short8 ag[AFR], bg[4];
      #pragma unroll
      for (int i = 0; i < AFR; ++i) {
        const int ar = wr + i * 16 + l15;
        ag[i] = *reinterpret_cast<const short8*>(reinterpret_cast<const char*>(As) +
                 ar * 128 + ((ks * 64 + l4 * 16) ^ ((ar & 7) << 4)));
      }
      #pragma unroll
      for (int j = 0; j < 4; ++j) {
        const int br = wc + j * 16 + l15;
        bg[j] = *reinterpret_cast<const short8*>(reinterpret_cast<const char*>(Bs) +
                 br * 128 + ((ks * 64 + l4 * 16) ^ ((br & 7) << 4)));
      }
      #pragma unroll
      for (int i = 0; i < AFR; ++i)
        #pragma unroll
        for (int j = 0; j < 4; ++j)
          acc[i][j] = __builtin_amdgcn_mfma_f32_16x16x32_bf16(ag[i], bg[j], acc[i][j], 0, 0, 0);
    }
    __syncthreads();
  }

  // epilogue: C row = (lane>>4)*4 + reg, col = lane&15 (m89-verified layout)
  #pragma unroll
  for (int j = 0; j < 4; ++j) {
    const int gcol = n0 + wc + j * 16 + l15;
    const float bb = bias[gcol];
    #pragma unroll
    for (int i = 0; i < AFR; ++i) {
      const int grow = m0 + wr + i * 16 + l4 * 4;
      if (mode == 2) {               // float32 output [M, DM]
        float* dst = reinterpret_cast<float*>(dstv);
        #pragma unroll
        for (int r = 0; r < 4; ++r)
          dst[(size_t)(grow + r) * DM + gcol] = acc[i][j][r] + bb;
      } else {
        u16* dst = reinterpret_cast<u16*>(dstv);
        const int b = grow >> 11, s = grow & (SEQ - 1);
        const int h = gcol >> 6, d = gcol & 63;
        if (mode == 0) {
          #pragma unroll
          for (int r = 0; r < 4; ++r)
            dst[((size_t)(b * H + h) * SEQ + s + r) * HD + d] = f2bf((acc[i][j][r] + bb) * outScale);
        } else {  // mode 1: V transposed — 4 consecutive s → one 8B store
          union { uint2 v; u16 e[4]; } pk;
          #pragma unroll
          for (int r = 0; r < 4; ++r) pk.e[r] = f2bf(acc[i][j][r] + bb);
          *reinterpret_cast<uint2*>(dst + ((size_t)(b * H + h) * HD + d) * SEQ + s) = pk.v;
        }
      }
    }
  }
}

__global__ __launch_bounds__(256) void gemm_qkv_kernel(
    const float* __restrict__ xq, const float* __restrict__ xk, const float* __restrict__ xv,
    const u16* __restrict__ wT, const float* __restrict__ bq, const float* __restrict__ bk,
    const float* __restrict__ bv, u16* __restrict__ Qb, u16* __restrict__ Kb, u16* __restrict__ Vtb)
{
  // 1152 blocks = 8 x 144: XCD-chunked bijective swizzle (T1)
  const int flat = blockIdx.z * 384 + blockIdx.y * 6 + blockIdx.x;
  const int nb = (flat & 7) * 144 + (flat >> 3);
  const int z = nb / 384, rem = nb % 384;
  const int by = rem / 6, bx = rem % 6;
  const float* A    = z == 0 ? xq : z == 1 ? xk : xv;
  const u16* Bt     = wT + (size_t)z * DM * DM;
  const float* bias = z == 0 ? bq : z == 1 ? bk : bv;
  u16* dst          = z == 0 ? Qb : z == 1 ? Kb : Vtb;
  const float sc    = z == 1 ? C_SM : 1.0f;   // fold softmax scale*log2e into K
  gemm_core<64, true>(A, Bt, bias, dst, z == 2 ? 1 : 0, bx, by, sc);
}

__global__ __launch_bounds__(256) void gemm_o_kernel(const u16* __restrict__ A, const u16* __restrict__ woT,
                                                     const float* __restrict__ bo, float* __restrict__ out)
{
  const int flat = blockIdx.y * 6 + blockIdx.x;        // 768 = 8 x 96
  const int nb = (flat & 7) * 96 + (flat >> 3);
  gemm_core<32, false>(A, woT, bo, out, 2, nb % 6, nb / 6, 1.0f);
}

// ---------------- flash attention: QBLK=64, KVBLK=128, 16 iters ----------------
// Swapped-QK^T, no max-tracking (K pre-scaled into exp2 domain), l via ones-MFMA.
// Double-buffered K/V (global_load_lds, pre-swizzled source), 1 barrier+1 vmcnt
// drain per 128 KV rows. K rows 128B: swz ^(row&7)<<4; V^T/P rows 256B: ^(row&15)<<4.
__global__ __launch_bounds__(256) void attn_kernel(const u16* __restrict__ Q, const u16* __restrict__ K,
                                                   const u16* __restrict__ Vt, u16* __restrict__ attn)
{
  __shared__ u16 Ks[2][128 * 64];   // [krow][d], rows 128 B
  __shared__ u16 Vs[2][64 * 128];   // [d][t],   rows 256 B
  __shared__ u16 Ps[4][16 * 128];   // per-wave P, rows 256 B; Q staged in Ps[0..1]
  const int t = threadIdx.x;
  const int lane = t & 63, w = t >> 6;
  const int l15 = lane & 15, l4 = lane >> 4;
  const int flat = blockIdx.y * 32 + blockIdx.x;       // 768 = 8 x 96 (T1)
  const int nbid = (flat & 7) * 96 + (flat >> 3);
  const int q0 = (nbid & 31) * 64;
  const int bh = nbid >> 5;
  const size_t qbase  = ((size_t)bh * SEQ + q0) * HD;
  const size_t kbase0 = (size_t)bh * SEQ * HD;
  const size_t vtbase = (size_t)bh * HD * SEQ;

  // K/Q staging: chunk ci = 1024B = 8 rows x 128B; lane: row ci*8+(lane>>3),
  // pre-swizzled col 8*((lane&7)^(row&7)).
  const int krow8 = lane >> 3;
  const int kcol  = ((lane & 7) ^ krow8) * 8;
  // V staging: chunk ci = 1024B = 4 rows x 256B; lane: d-row ci*4+(lane>>4),
  // pre-swizzled col 8*((lane&15)^(d&15)).
  const int vrow4 = lane >> 4;

  u16* Qstage = &Ps[0][0];
  #pragma unroll
  for (int j = 0; j < 2; ++j) {
    const int ci = w * 2 + j;
    gl2lds16(Q + qbase + (size_t)(ci * 8 + krow8) * HD + kcol, &Qstage[ci * 512]);
  }
  #pragma unroll
  for (int j = 0; j < 4; ++j) {
    const int ci = w * 4 + j;
    const int kr = ci * 8 + krow8;
    gl2lds16(K + kbase0 + (size_t)kr * HD + kcol, &Ks[0][ci * 512]);
    const int dv = ci * 4 + vrow4;
    const int vc = ((lane & 15) ^ (dv & 15)) * 8;
    gl2lds16(Vt + vtbase + (size_t)dv * SEQ + vc, &Vs[0][ci * 512]);
  }
  asm volatile("s_waitcnt vmcnt(8)" ::: "memory");   // my Q loads landed
  __builtin_amdgcn_s_barrier();                      // everyone's Q landed

  short8 qf[2];
  {
    const int qr = w * 16 + l15;
    #pragma unroll
    for (int ks = 0; ks < 2; ++ks)
      qf[ks] = *reinterpret_cast<const short8*>(reinterpret_cast<const char*>(Qstage) +
               qr * 128 + ((ks * 64 + l4 * 16) ^ ((qr & 7) << 4)));
  }
  asm volatile("s_waitcnt lgkmcnt(0)" ::: "memory"); // qf in regs
  __builtin_amdgcn_s_barrier();                      // all waves done with Q region

  short8 ones;
  #pragma unroll
  for (int j = 0; j < 8; ++j) ones[j] = (short)0x3F80;  // bf16 1.0

  f32x4 oacc[4] = {};
  f32x4 accL = {};
  char* Pw = reinterpret_cast<char*>(Ps[w]);
  const int pswz = l15 << 4;
  int cur = 0;

  for (int kt = 0; kt < SEQ / 128; ++kt) {
    asm volatile("s_waitcnt vmcnt(0)" ::: "memory"); // my K/V tile-kt loads landed
    __builtin_amdgcn_s_barrier();                    // everyone's landed; prev reads done

    if (kt + 1 < SEQ / 128) {                        // async prefetch next tile
      const int nxt = cur ^ 1;
      #pragma unroll
      for (int j = 0; j < 4; ++j) {
        const int ci = w * 4 + j;
        const int kr = ci * 8 + krow8;
        gl2lds16(K + kbase0 + (size_t)((kt + 1) * 128 + kr) * HD + kcol, &Ks[nxt][ci * 512]);
        const int dv = ci * 4 + vrow4;
        const int vc = ((lane & 15) ^ (dv & 15)) * 8;
        gl2lds16(Vt + vtbase + (size_t)dv * SEQ + (kt + 1) * 128 + vc, &Vs[nxt][ci * 512]);
      }
    }

    // S^T: sacc[kb] holds S[k = kb*16 + l4*4 + r][q = l15], exp2 domain
    f32x4 sacc[8] = {};
    __builtin_amdgcn_s_setprio(1);
    #pragma unroll
    for (int ks = 0; ks < 2; ++ks) {
      #pragma unroll
      for (int kb = 0; kb < 8; ++kb) {
        const int krw = kb * 16 + l15;
        short8 kf = *reinterpret_cast<const short8*>(reinterpret_cast<const char*>(Ks[cur]) +
                    krw * 128 + ((ks * 64 + l4 * 16) ^ ((krw & 7) << 4)));
        sacc[kb] = __builtin_amdgcn_mfma_f32_16x16x32_bf16(kf, qf[ks], sacc[kb], 0, 0, 0);
      }
    }
    __builtin_amdgcn_s_setprio(0);

    // P = exp2(S'), pack to bf16, write per-wave P rows (256 B, swizzled)
    #pragma unroll
    for (int kb = 0; kb < 8; ++kb) {
      const float p0 = exp2f(sacc[kb][0]);
      const float p1 = exp2f(sacc[kb][1]);
      const float p2 = exp2f(sacc[kb][2]);
      const float p3 = exp2f(sacc[kb][3]);
      uint2 pk;
      pk.x = cvt_pk_bf16(p0, p1);
      pk.y = cvt_pk_bf16(p2, p3);
      *reinterpret_cast<uint2*>(Pw + (l15 * 256 + ((kb * 32 + l4 * 8) ^ pswz))) = pk;
    }

    // PV + row-sum over 128 t: 4 k-slices of 32
    __builtin_amdgcn_s_setprio(1);
    #pragma unroll
    for (int ks2 = 0; ks2 < 4; ++ks2) {
      short8 pf = *reinterpret_cast<const short8*>(Pw +
                  (l15 * 256 + ((ks2 * 64 + l4 * 16) ^ pswz)));
      accL = __builtin_amdgcn_mfma_f32_16x16x32_bf16(pf, ones, accL, 0, 0, 0);
      #pragma unroll
      for (int nb = 0; nb < 4; ++nb) {
        const int vrw = nb * 16 + l15;
        short8 vf = *reinterpret_cast<const short8*>(reinterpret_cast<const char*>(Vs[cur]) +
                    vrw * 256 + ((ks2 * 64 + l4 * 16) ^ ((vrw & 15) << 4)));
        oacc[nb] = __builtin_amdgcn_mfma_f32_16x16x32_bf16(pf, vf, oacc[nb], 0, 0, 0);
      }
    }
    __builtin_amdgcn_s_setprio(0);
    cur ^= 1;
  }

  // normalize + store merged-head layout [B,S,H*HD]; accL rows align with oacc rows
  const int b = bh / H, h = bh % H;
  #pragma unroll
  for (int r = 0; r < 4; ++r) {
    const float inv = 1.f / accL[r];
    const int srow2 = q0 + w * 16 + l4 * 4 + r;
    const size_t base = ((size_t)(b * SEQ + srow2)) * DM + h * HD;
    #pragma unroll
    for (int nb = 0; nb < 4; ++nb)
      attn[base + nb * 16 + l15] = f2bf(oacc[nb][r] * inv);
  }
}

extern "C" void kernel_launch(void* const* d_in, const int* in_sizes, int n_in,
                              void* d_out, int out_size, void* d_ws, size_t ws_size,
                              hipStream_t stream)
{
  const float* q  = (const float*)d_in[0];
  const float* k  = (const float*)d_in[1];
  const float* v  = (const float*)d_in[2];
  const float* wq = (const float*)d_in[3];
  const float* bq = (const float*)d_in[4];
  const float* wk = (const float*)d_in[5];
  const float* bk = (const float*)d_in[6];
  const float* wv = (const float*)d_in[7];
  const float* bv = (const float*)d_in[8];
  const float* wo = (const float*)d_in[9];
  const float* bo = (const float*)d_in[10];

  u16* ws = (u16*)d_ws;
  const size_t WSZ = (size_t)DM * DM;       // 589,824
  const size_t TSZ = (size_t)MROWS * DM;    // 3,145,728
  u16* wT  = ws;                 // wqT, wkT, wvT, woT (4 x WSZ)
  u16* Qb  = ws + 4 * WSZ;       // [B,H,S,HD]
  u16* Kb  = Qb + TSZ;           // [B,H,S,HD], pre-scaled by C_SM
  u16* Vtb = Kb + TSZ;           // [B,H,HD,S]
  u16* Ab  = Vtb + TSZ;          // [M, DM] attention output (merged heads)

  transpose_w4<<<dim3(12, 12, 4), 256, 0, stream>>>(wq, wk, wv, wo, wT);
  gemm_qkv_kernel<<<dim3(6, 64, 3), 256, 0, stream>>>(q, k, v, wT, bq, bk, bv, Qb, Kb, Vtb);
  attn_kernel<<<dim3(SEQ / 64, BATCH * H), 256, 0, stream>>>(Qb, Kb, Vtb, Ab);
  gemm_o_kernel<<<dim3(6, 128), 256, 0, stream>>>(Ab, wT + 3 * WSZ, bo, (float*)d_out);
}

// Round 10
// 116.515 us; speedup vs baseline: 1.0213x; 1.0213x over previous
//
#include <hip/hip_runtime.h>

#define H 12
#define DM 768
#define HD 64
#define SEQ 2048
#define BATCH 2
#define MROWS (BATCH*SEQ)   // 4096

typedef __attribute__((ext_vector_type(8))) short short8;    // 8 bf16 (4 VGPRs)
typedef __attribute__((ext_vector_type(4))) float f32x4;
typedef __attribute__((ext_vector_type(16))) float f32x16;
using u16 = unsigned short;
using u32 = unsigned int;

__device__ __forceinline__ float bf2f(u16 u) { return __uint_as_float(((u32)u) << 16); }
__device__ __forceinline__ u16 f2bf(float x) {
  u32 u = __float_as_uint(x);
  return (u16)((u + 0x7fffu + ((u >> 16) & 1u)) >> 16);   // RNE
}
// packed f32x2 -> bf16x2 (RNE), single instruction (T12 recipe: no builtin on gfx950)
__device__ __forceinline__ u32 cvt_pk_bf16(float lo, float hi) {
  u32 r;
  asm("v_cvt_pk_bf16_f32 %0, %1, %2" : "=v"(r) : "v"(lo), "v"(hi));
  return r;
}
// async global->LDS, 16B per lane; LDS dest = wave-uniform base + lane*16 (m97/m104)
__device__ __forceinline__ void gl2lds16(const u16* __restrict__ g, u16* l) {
  __builtin_amdgcn_global_load_lds(
      (const __attribute__((address_space(1))) unsigned int*)g,
      (__attribute__((address_space(3))) unsigned int*)l,
      16, 0, 0);
}

#define C_SM 0.18033688011112042f   // (1/sqrt(64)) * log2(e), folded into K

// ------------- weight transpose + f32->bf16: dst[e*768+d] = bf16(src[d*768+e]) -------------
__global__ __launch_bounds__(256) void transpose_w4(const float* __restrict__ w0, const float* __restrict__ w1,
                                                    const float* __restrict__ w2, const float* __restrict__ w3,
                                                    u16* __restrict__ dst0)
{
  __shared__ u16 Ts[64][72];                 // +8 pad, rows 144 B (16B-aligned)
  const float* src = blockIdx.z == 0 ? w0 : blockIdx.z == 1 ? w1 : blockIdx.z == 2 ? w2 : w3;
  u16* dst = dst0 + (size_t)blockIdx.z * DM * DM;
  const int t = threadIdx.x;
  const int r0 = blockIdx.y * 64, c0 = blockIdx.x * 64;
  const int row = t >> 2, cq = (t & 3) * 16;
  const float* sp = src + (size_t)(r0 + row) * DM + c0 + cq;
  #pragma unroll
  for (int g = 0; g < 4; ++g) {
    float4 a = *reinterpret_cast<const float4*>(sp + g * 4);
    Ts[row][cq + g * 4 + 0] = f2bf(a.x);
    Ts[row][cq + g * 4 + 1] = f2bf(a.y);
    Ts[row][cq + g * 4 + 2] = f2bf(a.z);
    Ts[row][cq + g * 4 + 3] = f2bf(a.w);
  }
  __syncthreads();
  union { uint4 v[2]; u16 e[16]; } pk;
  #pragma unroll
  for (int j = 0; j < 16; ++j) pk.e[j] = Ts[cq + j][row];
  uint4* dp = reinterpret_cast<uint4*>(dst + (size_t)(c0 + row) * DM + r0 + cq);
  dp[0] = pk.v[0];
  dp[1] = pk.v[1];
}

// ---------------- GEMM: C[m][n] = (A[m][:] . Bt[n][:] + bias[n]) * outScale ----------------
// BM x 128 tile, BK=64, 4 waves, wave-tile (BM/2) x 64. Inline staging,
// XOR swizzle byte ^= (row&7)<<4 on write and read (T2, G4). Small BM for occupancy.
template<int BM, bool AF32>
__device__ __forceinline__ void gemm_core(const void* __restrict__ Av, const u16* __restrict__ Bt,
                                          const float* __restrict__ bias, void* __restrict__ dstv,
                                          int mode, int bx, int by, float outScale)
{
  constexpr int AFR = BM / 32;        // A-frags per wave (M dir)
  constexpr int ACH = BM / 32;        // A staging chunks
  __shared__ u16 As[BM * 64];
  __shared__ u16 Bs[128 * 64];
  const int t = threadIdx.x;
  const int lane = t & 63, w = t >> 6;
  const int l15 = lane & 15, l4 = lane >> 4;
  const int m0 = by * BM, n0 = bx * 128;
  const int wr = (w >> 1) * (BM / 2), wc = (w & 1) * 64;

  f32x4 acc[AFR][4] = {};

  for (int kt = 0; kt < DM / 64; ++kt) {
    const int k0 = kt * 64;
    #pragma unroll
    for (int c = 0; c < ACH; ++c) {           // A tile: BM x 64
      const int id = c * 256 + t;
      const int row = id >> 3, xc = id & 7;
      const int db = row * 128 + ((xc * 16) ^ ((row & 7) << 4));
      if (AF32) {
        const float* Af = reinterpret_cast<const float*>(Av) + (size_t)(m0 + row) * DM + k0 + xc * 8;
        float4 a0 = *reinterpret_cast<const float4*>(Af);
        float4 a1 = *reinterpret_cast<const float4*>(Af + 4);
        uint4 v;
        v.x = cvt_pk_bf16(a0.x, a0.y);
        v.y = cvt_pk_bf16(a0.z, a0.w);
        v.z = cvt_pk_bf16(a1.x, a1.y);
        v.w = cvt_pk_bf16(a1.z, a1.w);
        *reinterpret_cast<uint4*>(reinterpret_cast<char*>(As) + db) = v;
      } else {
        uint4 va = *reinterpret_cast<const uint4*>(reinterpret_cast<const u16*>(Av) +
                   (size_t)(m0 + row) * DM + k0 + xc * 8);
        *reinterpret_cast<uint4*>(reinterpret_cast<char*>(As) + db) = va;
      }
    }
    #pragma unroll
    for (int c = 0; c < 4; ++c) {             // B tile: 128 x 64
      const int id = c * 256 + t;
      const int row = id >> 3, xc = id & 7;
      const int db = row * 128 + ((xc * 16) ^ ((row & 7) << 4));
      uint4 vb = *reinterpret_cast<const uint4*>(Bt + (size_t)(n0 + row) * DM + k0 + xc * 8);
      *reinterpret_cast<uint4*>(reinterpret_cast<char*>(Bs) + db) = vb;
    }
    __syncthreads();
    #pragma unroll
    for (int ks = 0; ks < 2; ++ks) {
      short8 ag[AFR], bg[4];
      #pragma unroll
      for (int i = 0; i < AFR; ++i) {
        const int ar = wr + i * 16 + l15;
        ag[i] = *reinterpret_cast<const short8*>(reinterpret_cast<const char*>(As) +
                 ar * 128 + ((ks * 64 + l4 * 16) ^ ((ar & 7) << 4)));
      }
      #pragma unroll
      for (int j = 0; j < 4; ++j) {
        const int br = wc + j * 16 + l15;
        bg[j] = *reinterpret_cast<const short8*>(reinterpret_cast<const char*>(Bs) +
                 br * 128 + ((ks * 64 + l4 * 16) ^ ((br & 7) << 4)));
      }
      #pragma unroll
      for (int i = 0; i < AFR; ++i)
        #pragma unroll
        for (int j = 0; j < 4; ++j)
          acc[i][j] = __builtin_amdgcn_mfma_f32_16x16x32_bf16(ag[i], bg[j], acc[i][j], 0, 0, 0);
    }
    __syncthreads();
  }

  // epilogue: C row = (lane>>4)*4 + reg, col = lane&15 (m89-verified layout)
  #pragma unroll
  for (int j = 0; j < 4; ++j) {
    const int gcol = n0 + wc + j * 16 + l15;
    const float bb = bias[gcol];
    #pragma unroll
    for (int i = 0; i < AFR; ++i) {
      const int grow = m0 + wr + i * 16 + l4 * 4;
      if (mode == 2) {               // float32 output [M, DM]
        float* dst = reinterpret_cast<float*>(dstv);
        #pragma unroll
        for (int r = 0; r < 4; ++r)
          dst[(size_t)(grow + r) * DM + gcol] = acc[i][j][r] + bb;
      } else {
        u16* dst = reinterpret_cast<u16*>(dstv);
        const int b = grow >> 11, s = grow & (SEQ - 1);
        const int h = gcol >> 6, d = gcol & 63;
        if (mode == 0) {
          #pragma unroll
          for (int r = 0; r < 4; ++r)
            dst[((size_t)(b * H + h) * SEQ + s + r) * HD + d] = f2bf((acc[i][j][r] + bb) * outScale);
        } else {  // mode 1: V transposed — 4 consecutive s → one 8B store
          union { uint2 v; u16 e[4]; } pk;
          #pragma unroll
          for (int r = 0; r < 4; ++r) pk.e[r] = f2bf(acc[i][j][r] + bb);
          *reinterpret_cast<uint2*>(dst + ((size_t)(b * H + h) * HD + d) * SEQ + s) = pk.v;
        }
      }
    }
  }
}

__global__ __launch_bounds__(256) void gemm_qkv_kernel(
    const float* __restrict__ xq, const float* __restrict__ xk, const float* __restrict__ xv,
    const u16* __restrict__ wT, const float* __restrict__ bq, const float* __restrict__ bk,
    const float* __restrict__ bv, u16* __restrict__ Qb, u16* __restrict__ Kb, u16* __restrict__ Vtb)
{
  // 1152 blocks = 8 x 144: XCD-chunked bijective swizzle (T1)
  const int flat = blockIdx.z * 384 + blockIdx.y * 6 + blockIdx.x;
  const int nb = (flat & 7) * 144 + (flat >> 3);
  const int z = nb / 384, rem = nb % 384;
  const int by = rem / 6, bx = rem % 6;
  const float* A    = z == 0 ? xq : z == 1 ? xk : xv;
  const u16* Bt     = wT + (size_t)z * DM * DM;
  const float* bias = z == 0 ? bq : z == 1 ? bk : bv;
  u16* dst          = z == 0 ? Qb : z == 1 ? Kb : Vtb;
  const float sc    = z == 1 ? C_SM : 1.0f;   // fold softmax scale*log2e into K
  gemm_core<64, true>(A, Bt, bias, dst, z == 2 ? 1 : 0, bx, by, sc);
}

__global__ __launch_bounds__(256) void gemm_o_kernel(const u16* __restrict__ A, const u16* __restrict__ woT,
                                                     const float* __restrict__ bo, float* __restrict__ out)
{
  const int flat = blockIdx.y * 6 + blockIdx.x;        // 768 = 8 x 96
  const int nb = (flat & 7) * 96 + (flat >> 3);
  gemm_core<32, false>(A, woT, bo, out, 2, nb % 6, nb / 6, 1.0f);
}

// ---------------- flash attention: QBLK=128 (4 waves x 32q), KVBLK=64, 32x32x16 MFMA ----------
// Swapped QK^T (S^T = mfma(K, Q)), no max-tracking (K pre-scaled into exp2 domain),
// P kept IN REGISTERS: PV A-frag built via 4x cvt_pk + 2x v_permlane32_swap_b32 per
// k-slice (lane<->lane^32 exchange matches the 32x32 A-frag k-split exactly).
// l summed in-lane, closed by one shfl_xor(32) + epilogue shfl per output row.
// K/V double-buffered via global_load_lds w/ pre-swizzled source; 1 barrier/iter.
__global__ __launch_bounds__(256) void attn_kernel(const u16* __restrict__ Q, const u16* __restrict__ K,
                                                   const u16* __restrict__ Vt, u16* __restrict__ attn)
{
  __shared__ u16 Ks[2][64 * 64];   // [kv][d] rows 128B
  __shared__ u16 Vs[2][64 * 64];   // [d][t]  rows 128B
  __shared__ u16 Qs[128 * 64];     // [q][d]  rows 128B
  const int t = threadIdx.x;
  const int lane = t & 63, w = t >> 6;
  const int l31 = lane & 31, hi = lane >> 5;
  const int flat = blockIdx.y * 16 + blockIdx.x;       // 384 = 8 x 48 (T1)
  const int nbid = (flat & 7) * 48 + (flat >> 3);
  const int q0 = (nbid & 15) * 128;
  const int bh = nbid >> 4;
  const size_t qbase  = ((size_t)bh * SEQ + q0) * HD;
  const size_t kbase0 = (size_t)bh * SEQ * HD;
  const size_t vtbase = (size_t)bh * HD * SEQ;

  // staging: chunk = 1024B = 8 rows x 128B; lane covers 16B at chunk + lane*16;
  // row-in-chunk = lane>>3; pre-swizzled global col = 8*((lane&7)^(row&7)).
  const int r8 = lane >> 3;
  const int pcol = ((lane & 7) ^ r8) * 8;

  // Q: 16 chunks; wave w stages ci = w*4+j == its OWN q-rows w*32..w*32+31
  #pragma unroll
  for (int j = 0; j < 4; ++j) {
    const int ci = w * 4 + j;
    gl2lds16(Q + qbase + (size_t)(ci * 8 + r8) * HD + pcol, &Qs[ci * 512]);
  }
  // K/V tile 0: 8 chunks each; wave w stages ci = w*2+j
  #pragma unroll
  for (int j = 0; j < 2; ++j) {
    const int ci = w * 2 + j;
    const int row = ci * 8 + r8;
    gl2lds16(K + kbase0 + (size_t)row * HD + pcol, &Ks[0][ci * 512]);
    gl2lds16(Vt + vtbase + (size_t)row * SEQ + pcol, &Vs[0][ci * 512]);
  }
  asm volatile("s_waitcnt vmcnt(4)" ::: "memory");   // my Q chunks landed (own rows only)

  // Q-frags: B-operand, lane holds Q[q = w*32 + l31][d = ks*16 + hi*8 + j]
  short8 qf[4];
  {
    const int qr = w * 32 + l31;
    #pragma unroll
    for (int ks = 0; ks < 4; ++ks)
      qf[ks] = *reinterpret_cast<const short8*>(reinterpret_cast<const char*>(Qs) +
               qr * 128 + (((ks * 32 + hi * 16)) ^ ((qr & 7) << 4)));
  }

  f32x16 oacc[2] = {};
  float l_s = 0.f;
  int cur = 0;

  for (int kt = 0; kt < SEQ / 64; ++kt) {
    asm volatile("s_waitcnt vmcnt(0)" ::: "memory"); // K/V tile-kt landed
    __builtin_amdgcn_s_barrier();                    // all waves ready; prev reads done

    if (kt + 1 < SEQ / 64) {                         // async prefetch next tile
      const int nxt = cur ^ 1;
      #pragma unroll
      for (int j = 0; j < 2; ++j) {
        const int ci = w * 2 + j;
        const int row = ci * 8 + r8;
        gl2lds16(K + kbase0 + (size_t)((kt + 1) * 64 + row) * HD + pcol, &Ks[nxt][ci * 512]);
        gl2lds16(Vt + vtbase + (size_t)row * SEQ + (kt + 1) * 64 + pcol, &Vs[nxt][ci * 512]);
      }
    }

    // QK^T: s0/s1 = S^T tiles [kv 0-31 / 32-63][q = 32 own rows], exp2 domain.
    // C/D layout: col q = l31, row kv = (reg&3) + 8*(reg>>2) + 4*hi (+32 for s1)
    f32x16 s0 = {}, s1 = {};
    __builtin_amdgcn_s_setprio(1);
    #pragma unroll
    for (int ks = 0; ks < 4; ++ks) {
      const int cb = ks * 32 + hi * 16;
      short8 kf0 = *reinterpret_cast<const short8*>(reinterpret_cast<const char*>(Ks[cur]) +
                   l31 * 128 + (cb ^ ((l31 & 7) << 4)));
      short8 kf1 = *reinterpret_cast<const short8*>(reinterpret_cast<const char*>(Ks[cur]) +
                   (32 + l31) * 128 + (cb ^ ((l31 & 7) << 4)));
      s0 = __builtin_amdgcn_mfma_f32_32x32x16_bf16(kf0, qf[ks], s0, 0, 0, 0);
      s1 = __builtin_amdgcn_mfma_f32_32x32x16_bf16(kf1, qf[ks], s1, 0, 0, 0);
    }
    __builtin_amdgcn_s_setprio(0);

    // P = exp2(S'); in-lane partial row-sum
    float p0[16], p1[16], psum = 0.f;
    #pragma unroll
    for (int r = 0; r < 16; ++r) {
      p0[r] = exp2f(s0[r]);
      p1[r] = exp2f(s1[r]);
      psum += p0[r] + p1[r];
    }
    l_s += psum;

    // PV: O[q][d] += P[q][kv] V[kv][d]; A-frag per k-slice (16 kv) built in-register:
    // own regs hold kv == 4*hi (mod 8); partner (lane^32) holds the other half ->
    // swap(A0,B0): A0' = U0 (kv+0,+1), B0' = U2 (kv+4,+5); swap(A1,B1) -> U1,U3.
    __builtin_amdgcn_s_setprio(1);
    #pragma unroll
    for (int ks2 = 0; ks2 < 4; ++ks2) {
      const float* P = (ks2 < 2) ? p0 : p1;    // ks2 compile-time after unroll
      const int ro = (ks2 & 1) * 8;
      u32 a0 = cvt_pk_bf16(P[ro + 0], P[ro + 1]);
      u32 a1 = cvt_pk_bf16(P[ro + 2], P[ro + 3]);
      u32 b0 = cvt_pk_bf16(P[ro + 4], P[ro + 5]);
      u32 b1 = cvt_pk_bf16(P[ro + 6], P[ro + 7]);
      asm volatile("v_permlane32_swap_b32 %0, %1" : "+v"(a0), "+v"(b0));
      asm volatile("v_permlane32_swap_b32 %0, %1" : "+v"(a1), "+v"(b1));
      union { u32 u[4]; short8 s; } pa;
      pa.u[0] = a0; pa.u[1] = a1; pa.u[2] = b0; pa.u[3] = b1;
      const int cb2 = ks2 * 32 + hi * 16;
      #pragma unroll
      for (int dt = 0; dt < 2; ++dt) {
        const int vr = dt * 32 + l31;
        short8 vf = *reinterpret_cast<const short8*>(reinterpret_cast<const char*>(Vs[cur]) +
                    vr * 128 + (cb2 ^ ((vr & 7) << 4)));
        oacc[dt] = __builtin_amdgcn_mfma_f32_32x32x16_bf16(pa.s, vf, oacc[dt], 0, 0, 0);
      }
    }
    __builtin_amdgcn_s_setprio(0);
    cur ^= 1;
  }

  // finalize: full row-sums, normalize, store merged-head [B,S,H*HD]
  const float l_tot = l_s + __shfl_xor(l_s, 32);
  const int b = bh / H, h = bh % H;
  #pragma unroll
  for (int r = 0; r < 16; ++r) {
    const int qo = (r & 3) + 8 * (r >> 2) + 4 * hi;   // C/D row within wave's 32 q
    const float inv = 1.f / __shfl(l_tot, qo);
    const int qg = q0 + w * 32 + qo;
    const size_t base = ((size_t)(b * SEQ + qg)) * DM + h * HD;
    attn[base + l31]      = f2bf(oacc[0][r] * inv);
    attn[base + 32 + l31] = f2bf(oacc[1][r] * inv);
  }
}

extern "C" void kernel_launch(void* const* d_in, const int* in_sizes, int n_in,
                              void* d_out, int out_size, void* d_ws, size_t ws_size,
                              hipStream_t stream)
{
  const float* q  = (const float*)d_in[0];
  const float* k  = (const float*)d_in[1];
  const float* v  = (const float*)d_in[2];
  const float* wq = (const float*)d_in[3];
  const float* bq = (const float*)d_in[4];
  const float* wk = (const float*)d_in[5];
  const float* bk = (const float*)d_in[6];
  const float* wv = (const float*)d_in[7];
  const float* bv = (const float*)d_in[8];
  const float* wo = (const float*)d_in[9];
  const float* bo = (const float*)d_in[10];

  u16* ws = (u16*)d_ws;
  const size_t WSZ = (size_t)DM * DM;       // 589,824
  const size_t TSZ = (size_t)MROWS * DM;    // 3,145,728
  u16* wT  = ws;                 // wqT, wkT, wvT, woT (4 x WSZ)
  u16* Qb  = ws + 4 * WSZ;       // [B,H,S,HD]
  u16* Kb  = Qb + TSZ;           // [B,H,S,HD], pre-scaled by C_SM
  u16* Vtb = Kb + TSZ;           // [B,H,HD,S]
  u16* Ab  = Vtb + TSZ;          // [M, DM] attention output (merged heads)

  transpose_w4<<<dim3(12, 12, 4), 256, 0, stream>>>(wq, wk, wv, wo, wT);
  gemm_qkv_kernel<<<dim3(6, 64, 3), 256, 0, stream>>>(q, k, v, wT, bq, bk, bv, Qb, Kb, Vtb);
  attn_kernel<<<dim3(16, BATCH * H), 256, 0, stream>>>(Qb, Kb, Vtb, Ab);
  gemm_o_kernel<<<dim3(6, 128), 256, 0, stream>>>(Ab, wT + 3 * WSZ, bo, (float*)d_out);
}